// Round 7
// baseline (221.130 us; speedup 1.0000x reference)
//
#include <hip/hip_runtime.h>

#define DM 1024
#define NW 16384

typedef __attribute__((ext_vector_type(8))) short short8;
typedef __attribute__((ext_vector_type(4))) float f32x4;

// ws layout (float offsets). High-water = OFF_PART + 512*16*1024 = 8437760 floats
// (~32.2 MiB) — fits the ws buffer (256 MiB poison fills observed in rocprof).
#define OFF_AH   1024       // A-frag hi: 16384 shorts = 8192 floats
#define OFF_AL   9216       // A-frag lo: 16384 shorts
#define OFF_D0   17408      // 16
#define OFF_SP   17440      // Spart[16][512] = 8192 (per-head, per-chunk denom partials)
#define OFF_X    25632      // 1024
#define OFF_W    26656      // 16384 -> ends 43040
#define OFF_PART 49152      // part[512][16][1024] = 8388608 floats

// fp32 -> bf16 round-to-nearest-even (returns bits)
__device__ __forceinline__ unsigned short f2bf(float f) {
  unsigned int u = __float_as_uint(f);
  return (unsigned short)((u + 0x7fffu + ((u >> 16) & 1u)) >> 16);
}

// Scheduling fence: loads issued before this cannot be sunk past it by the
// pre-RA scheduler. Used ONCE per load granule to make the software pipeline
// real in the ISA (r4/r6 showed the compiler otherwise collapses it: VGPR=88).
#define SB() __builtin_amdgcn_sched_barrier(0)

// Barrier that drains only LDS ops (keeps global loads in flight across it).
__device__ __forceinline__ void barrier_lgkm() {
  asm volatile("s_waitcnt lgkmcnt(0)" ::: "memory");
  __builtin_amdgcn_s_barrier();
  __builtin_amdgcn_sched_barrier(0);
}

// out[r] = dot(W[r,:], v) + b[r]   — one wave per row, 1024 waves
__global__ __launch_bounds__(256) void k_rowdot(const float* __restrict__ W,
                                                const float* __restrict__ v,
                                                const float* __restrict__ b,
                                                float* __restrict__ out) {
  const int wave = (blockIdx.x * 256 + threadIdx.x) >> 6;
  const int lane = threadIdx.x & 63;
  const float* row = W + (size_t)wave * DM + 4 * lane;
  float s = 0.f;
#pragma unroll
  for (int j = 0; j < 4; ++j) {
    float4 a = *(const float4*)(row + j * 256);
    float4 x = *(const float4*)(v + j * 256 + 4 * lane);
    s += a.x * x.x + a.y * x.y + a.z * x.z + a.w * x.w;
  }
#pragma unroll
  for (int off = 32; off; off >>= 1) s += __shfl_xor(s, off, 64);
  if (lane == 0) out[wave] = s + b[wave];
}

// Fused: q_h = query@Wq_h^T + bq (LDS), then c[h,m] = q_h · Wk[h*64+:,m],
// emitted directly as MFMA A-fragments (bf16 hi+lo). d0[h] = q_h·bk_h.
// Also zeroes w (16384 floats) for k_wred's atomics.
__global__ __launch_bounds__(256) void k_qck(const float* __restrict__ Wq,
                                             const float* __restrict__ bq,
                                             const float* __restrict__ query,
                                             const float* __restrict__ Wk,
                                             const float* __restrict__ bk,
                                             short* __restrict__ Ah,
                                             short* __restrict__ Al,
                                             float* __restrict__ d0,
                                             float* __restrict__ w) {
  const int h = blockIdx.x >> 2;
  const int mc = blockIdx.x & 3;
  const int t = threadIdx.x;
  const int lane = t & 63;
  const int wv = t >> 6;
  __shared__ float qh[64];
  w[blockIdx.x * 256 + t] = 0.f;          // 64*256 = 16384 threads exactly
  float4 qv[4];
#pragma unroll
  for (int j = 0; j < 4; ++j) qv[j] = *(const float4*)(query + j * 256 + 4 * lane);
  // phase 1: q_h rows, 4 rows per wave-iteration (16 loads in flight)
#pragma unroll 1
  for (int ii = 0; ii < 16; ii += 4) {
    float4 a[4][4];
#pragma unroll
    for (int r = 0; r < 4; ++r) {
      const float* rp = Wq + (size_t)(h * 64 + 4 * (ii + r) + wv) * DM + 4 * lane;
#pragma unroll
      for (int j = 0; j < 4; ++j) a[r][j] = *(const float4*)(rp + j * 256);
    }
    float s[4] = {0.f, 0.f, 0.f, 0.f};
#pragma unroll
    for (int r = 0; r < 4; ++r)
#pragma unroll
      for (int j = 0; j < 4; ++j)
        s[r] += a[r][j].x * qv[j].x + a[r][j].y * qv[j].y +
                a[r][j].z * qv[j].z + a[r][j].w * qv[j].w;
#pragma unroll
    for (int off = 32; off; off >>= 1)
#pragma unroll
      for (int r = 0; r < 4; ++r) s[r] += __shfl_xor(s[r], off, 64);
    if (lane == 0)
#pragma unroll
      for (int r = 0; r < 4; ++r)
        qh[4 * (ii + r) + wv] = s[r] + bq[h * 64 + 4 * (ii + r) + wv];
  }
  __syncthreads();
  // phase 2: c[h,m] = q_h · Wk column m
  const int m = mc * 256 + t;
  const float* Wp = Wk + (size_t)(h * 64) * DM + m;
  float s = 0.f;
#pragma unroll 2
  for (int db = 0; db < 8; ++db) {
    float wv8[8];
#pragma unroll
    for (int j = 0; j < 8; ++j) wv8[j] = Wp[(size_t)(db * 8 + j) * DM];
#pragma unroll
    for (int j = 0; j < 8; ++j) s = fmaf(qh[db * 8 + j], wv8[j], s);
  }
  unsigned short hu = f2bf(s);
  float hf = __uint_as_float(((unsigned int)hu) << 16);
  unsigned short lu = f2bf(s - hf);
  const int kb = m >> 5, q = (m >> 3) & 3, j = m & 7;
  const int idx = (kb * 64 + q * 16 + h) * 8 + j;
  Ah[idx] = (short)hu;
  Al[idx] = (short)lu;
  if (mc == 0 && t == 0) {
    float tt = 0.f;
    for (int d = 0; d < 64; ++d) tt += qh[d] * bk[h * 64 + d];
    d0[h] = tt;
  }
}

// Fused scores + PV, 512 blocks (2/CU), one 32-row chunk per block.
// Phase A: 4 waves = 2 tiles x 2-way K-split; MFMA bf16 hi/lo, 3-deep prefetch
//   with sched_barrier fences so the pipeline survives compilation.
// Phase B: thread owns 4 cols; 3-deep fenced value pipeline; first granule
//   issued BEFORE the lgkm-only phase barrier (rides across, no vmcnt drain).
__global__ __launch_bounds__(256, 2) void k_spv(const float* __restrict__ key,
                                                const float* __restrict__ value,
                                                const short* __restrict__ AhG,
                                                const short* __restrict__ AlG,
                                                const float* __restrict__ d0,
                                                float* __restrict__ part,
                                                float* __restrict__ Spart) {
  const int nb = blockIdx.x;              // 0..511 (32-row chunk)
  const int t = threadIdx.x;
  const int lane = t & 63;
  const int wv = t >> 6;                  // 0..3
  const int tile = wv >> 1;               // 0..1  -> 16-row tile
  const int khalf = wv & 1;               // K-split half
  const int nl = tile * 16 + (lane & 15); // local row 0..31
  const int n = nb * 32 + nl;
  const int quad = lane >> 4;
  const float* base = key + (size_t)n * DM + quad * 8;
  const short8* A8h = (const short8*)AhG;
  const short8* A8l = (const short8*)AlG;
  __shared__ float el[32 * 16];           // 2 KB
  __shared__ f32x4 sred[4][64];           // 4 KB

  short8 ah[3][4], al[3][4];
  float4 f0[3][4], f1[3][4];
  f32x4 acc0 = {0.f, 0.f, 0.f, 0.f};
  f32x4 acc1 = {0.f, 0.f, 0.f, 0.f};

#define LOADG(buf, g) { \
  _Pragma("unroll") for (int i = 0; i < 4; ++i) { \
    const int kb = khalf * 16 + (g) * 4 + i; \
    ah[buf][i] = A8h[kb * 64 + lane]; \
    al[buf][i] = A8l[kb * 64 + lane]; \
    f0[buf][i] = *(const float4*)(base + kb * 32); \
    f1[buf][i] = *(const float4*)(base + kb * 32 + 4); \
  } }

#define PROC(buf) { \
  _Pragma("unroll") for (int i = 0; i < 4; ++i) { \
    float ff[8] = {f0[buf][i].x, f0[buf][i].y, f0[buf][i].z, f0[buf][i].w, \
                   f1[buf][i].x, f1[buf][i].y, f1[buf][i].z, f1[buf][i].w}; \
    short8 bh, bl; \
    _Pragma("unroll") for (int j = 0; j < 8; ++j) { \
      unsigned short hu = f2bf(ff[j]); \
      bh[j] = (short)hu; \
      float hf = __uint_as_float(((unsigned int)hu) << 16); \
      bl[j] = (short)f2bf(ff[j] - hf); \
    } \
    if ((i & 1) == 0) { \
      acc0 = __builtin_amdgcn_mfma_f32_16x16x32_bf16(ah[buf][i], bh, acc0, 0, 0, 0); \
      acc0 = __builtin_amdgcn_mfma_f32_16x16x32_bf16(ah[buf][i], bl, acc0, 0, 0, 0); \
      acc0 = __builtin_amdgcn_mfma_f32_16x16x32_bf16(al[buf][i], bh, acc0, 0, 0, 0); \
    } else { \
      acc1 = __builtin_amdgcn_mfma_f32_16x16x32_bf16(ah[buf][i], bh, acc1, 0, 0, 0); \
      acc1 = __builtin_amdgcn_mfma_f32_16x16x32_bf16(ah[buf][i], bl, acc1, 0, 0, 0); \
      acc1 = __builtin_amdgcn_mfma_f32_16x16x32_bf16(al[buf][i], bh, acc1, 0, 0, 0); \
    } \
  } }

  // 3-deep pipeline over 4 granules; SB() pins each granule's issue point.
  LOADG(0, 0) SB();
  LOADG(1, 1) SB();
  LOADG(2, 2) SB();
  PROC(0)
  LOADG(0, 3) SB();
  PROC(1)
  PROC(2)
  PROC(0)
#undef LOADG
#undef PROC

  f32x4 at = acc0 + acc1;
  sred[wv][lane] = at;
  __syncthreads();                        // vmcnt naturally ~0 here
  if (khalf == 0) {
    f32x4 o = sred[wv + 1][lane];
    const float4 dv = *(const float4*)(d0 + quad * 4);
    float ex0 = __expf(at[0] + o[0] + dv.x);
    float ex1 = __expf(at[1] + o[1] + dv.y);
    float ex2 = __expf(at[2] + o[2] + dv.z);
    float ex3 = __expf(at[3] + o[3] + dv.w);
    *(float4*)&el[nl * 16 + quad * 4] = make_float4(ex0, ex1, ex2, ex3);
  }

  // Phase B setup: issue first value granule BEFORE the phase barrier; it stays
  // in flight across it (barrier drains lgkm only, not vmcnt).
  const float* vp = value + (size_t)(nb * 32) * DM + 4 * t;
  float4 vbuf[3][8];

#define LOADV(buf, g) { \
  _Pragma("unroll") for (int i = 0; i < 8; ++i) \
    vbuf[buf][i] = *(const float4*)(vp + (size_t)((g) * 8 + i) * DM); }

  LOADV(0, 0) SB();
  barrier_lgkm();
  LOADV(1, 1) SB();
  LOADV(2, 2) SB();

  if (t < 16) {                           // per-chunk denominator partial
    float s = 0.f;
#pragma unroll
    for (int r = 0; r < 32; ++r) s += el[r * 16 + t];
    Spart[t * 512 + nb] = s;
  }

  float4 acc[16];
#pragma unroll
  for (int h = 0; h < 16; ++h) acc[h] = make_float4(0.f, 0.f, 0.f, 0.f);

#define COMPV(buf, g) { \
  _Pragma("unroll") for (int i = 0; i < 8; ++i) { \
    const float4* er4 = (const float4*)&el[((g) * 8 + i) * 16]; \
    float4 e0 = er4[0], e1 = er4[1], e2 = er4[2], e3 = er4[3]; \
    float4 vvv = vbuf[buf][i]; \
    acc[0].x  = fmaf(e0.x, vvv.x, acc[0].x);  acc[0].y  = fmaf(e0.x, vvv.y, acc[0].y); \
    acc[0].z  = fmaf(e0.x, vvv.z, acc[0].z);  acc[0].w  = fmaf(e0.x, vvv.w, acc[0].w); \
    acc[1].x  = fmaf(e0.y, vvv.x, acc[1].x);  acc[1].y  = fmaf(e0.y, vvv.y, acc[1].y); \
    acc[1].z  = fmaf(e0.y, vvv.z, acc[1].z);  acc[1].w  = fmaf(e0.y, vvv.w, acc[1].w); \
    acc[2].x  = fmaf(e0.z, vvv.x, acc[2].x);  acc[2].y  = fmaf(e0.z, vvv.y, acc[2].y); \
    acc[2].z  = fmaf(e0.z, vvv.z, acc[2].z);  acc[2].w  = fmaf(e0.z, vvv.w, acc[2].w); \
    acc[3].x  = fmaf(e0.w, vvv.x, acc[3].x);  acc[3].y  = fmaf(e0.w, vvv.y, acc[3].y); \
    acc[3].z  = fmaf(e0.w, vvv.z, acc[3].z);  acc[3].w  = fmaf(e0.w, vvv.w, acc[3].w); \
    acc[4].x  = fmaf(e1.x, vvv.x, acc[4].x);  acc[4].y  = fmaf(e1.x, vvv.y, acc[4].y); \
    acc[4].z  = fmaf(e1.x, vvv.z, acc[4].z);  acc[4].w  = fmaf(e1.x, vvv.w, acc[4].w); \
    acc[5].x  = fmaf(e1.y, vvv.x, acc[5].x);  acc[5].y  = fmaf(e1.y, vvv.y, acc[5].y); \
    acc[5].z  = fmaf(e1.y, vvv.z, acc[5].z);  acc[5].w  = fmaf(e1.y, vvv.w, acc[5].w); \
    acc[6].x  = fmaf(e1.z, vvv.x, acc[6].x);  acc[6].y  = fmaf(e1.z, vvv.y, acc[6].y); \
    acc[6].z  = fmaf(e1.z, vvv.z, acc[6].z);  acc[6].w  = fmaf(e1.z, vvv.w, acc[6].w); \
    acc[7].x  = fmaf(e1.w, vvv.x, acc[7].x);  acc[7].y  = fmaf(e1.w, vvv.y, acc[7].y); \
    acc[7].z  = fmaf(e1.w, vvv.z, acc[7].z);  acc[7].w  = fmaf(e1.w, vvv.w, acc[7].w); \
    acc[8].x  = fmaf(e2.x, vvv.x, acc[8].x);  acc[8].y  = fmaf(e2.x, vvv.y, acc[8].y); \
    acc[8].z  = fmaf(e2.x, vvv.z, acc[8].z);  acc[8].w  = fmaf(e2.x, vvv.w, acc[8].w); \
    acc[9].x  = fmaf(e2.y, vvv.x, acc[9].x);  acc[9].y  = fmaf(e2.y, vvv.y, acc[9].y); \
    acc[9].z  = fmaf(e2.y, vvv.z, acc[9].z);  acc[9].w  = fmaf(e2.y, vvv.w, acc[9].w); \
    acc[10].x = fmaf(e2.z, vvv.x, acc[10].x); acc[10].y = fmaf(e2.z, vvv.y, acc[10].y); \
    acc[10].z = fmaf(e2.z, vvv.z, acc[10].z); acc[10].w = fmaf(e2.z, vvv.w, acc[10].w); \
    acc[11].x = fmaf(e2.w, vvv.x, acc[11].x); acc[11].y = fmaf(e2.w, vvv.y, acc[11].y); \
    acc[11].z = fmaf(e2.w, vvv.z, acc[11].z); acc[11].w = fmaf(e2.w, vvv.w, acc[11].w); \
    acc[12].x = fmaf(e3.x, vvv.x, acc[12].x); acc[12].y = fmaf(e3.x, vvv.y, acc[12].y); \
    acc[12].z = fmaf(e3.x, vvv.z, acc[12].z); acc[12].w = fmaf(e3.x, vvv.w, acc[12].w); \
    acc[13].x = fmaf(e3.y, vvv.x, acc[13].x); acc[13].y = fmaf(e3.y, vvv.y, acc[13].y); \
    acc[13].z = fmaf(e3.y, vvv.z, acc[13].z); acc[13].w = fmaf(e3.y, vvv.w, acc[13].w); \
    acc[14].x = fmaf(e3.z, vvv.x, acc[14].x); acc[14].y = fmaf(e3.z, vvv.y, acc[14].y); \
    acc[14].z = fmaf(e3.z, vvv.z, acc[14].z); acc[14].w = fmaf(e3.z, vvv.w, acc[14].w); \
    acc[15].x = fmaf(e3.w, vvv.x, acc[15].x); acc[15].y = fmaf(e3.w, vvv.y, acc[15].y); \
    acc[15].z = fmaf(e3.w, vvv.z, acc[15].z); acc[15].w = fmaf(e3.w, vvv.w, acc[15].w); \
  } }

  COMPV(0, 0)
  LOADV(0, 3) SB();
  COMPV(1, 1)
  COMPV(2, 2)
  COMPV(0, 3)
#undef LOADV
#undef COMPV

  float* pp = part + (size_t)nb * (16 * DM) + 4 * t;
#pragma unroll
  for (int h = 0; h < 16; ++h) *(float4*)(pp + (size_t)h * DM) = acc[h];
}

// w[o] += sum over 128 chunks (4-way split across q) — fully coalesced
__global__ __launch_bounds__(256) void k_wred(const float* __restrict__ part,
                                              float* __restrict__ w) {
  const int g = blockIdx.x * 256 + threadIdx.x;  // grid 256 blocks = 65536
  const int o = g & 16383;
  const int q = g >> 14;                         // 0..3
  float s = 0.f;
#pragma unroll 1
  for (int ib = 0; ib < 16; ++ib) {
    float x[8];
#pragma unroll
    for (int j = 0; j < 8; ++j)
      x[j] = part[(size_t)(q * 128 + ib * 8 + j) * 16384 + o];
#pragma unroll
    for (int j = 0; j < 8; ++j) s += x[j];
  }
  atomicAdd(w + o, s);
}

// x[r] = dot(Wv[r,:], w[h,:]) / S[h] + bv[r],  h = r>>6 — wave per row.
// S[h] reduced in-wave from Spart[h][0..511].
__global__ __launch_bounds__(256) void k_xproj(const float* __restrict__ Wv,
                                               const float* __restrict__ w,
                                               const float* __restrict__ bv,
                                               const float* __restrict__ Spart,
                                               float* __restrict__ x) {
  const int wave = (blockIdx.x * 256 + threadIdx.x) >> 6;
  const int lane = threadIdx.x & 63;
  const int h = wave >> 6;
  const float* vec = w + (size_t)h * DM;
  const float* row = Wv + (size_t)wave * DM + 4 * lane;
  const float* sp = Spart + (size_t)h * 512;
  float s = 0.f, ss = 0.f;
#pragma unroll
  for (int i = 0; i < 8; ++i) ss += sp[i * 64 + lane];
#pragma unroll
  for (int j = 0; j < 4; ++j) {
    float4 a = *(const float4*)(row + j * 256);
    float4 x4 = *(const float4*)(vec + j * 256 + 4 * lane);
    s += a.x * x4.x + a.y * x4.y + a.z * x4.z + a.w * x4.w;
  }
#pragma unroll
  for (int off = 32; off; off >>= 1) {
    s += __shfl_xor(s, off, 64);
    ss += __shfl_xor(ss, off, 64);
  }
  if (lane == 0) x[wave] = s / ss + bv[wave];
}

extern "C" void kernel_launch(void* const* d_in, const int* in_sizes, int n_in,
                              void* d_out, int out_size, void* d_ws, size_t ws_size,
                              hipStream_t stream) {
  const float* query = (const float*)d_in[0];
  const float* key   = (const float*)d_in[1];
  const float* value = (const float*)d_in[2];
  const float* Wq    = (const float*)d_in[3];
  const float* bq    = (const float*)d_in[4];
  const float* Wk    = (const float*)d_in[5];
  const float* bk    = (const float*)d_in[6];
  const float* Wv    = (const float*)d_in[7];
  const float* bv    = (const float*)d_in[8];
  const float* Wo    = (const float*)d_in[9];
  const float* bo    = (const float*)d_in[10];
  float* out = (float*)d_out;
  float* ws  = (float*)d_ws;
  short* Ah  = (short*)(ws + OFF_AH);
  short* Al  = (short*)(ws + OFF_AL);

  k_qck    <<<64,  256, 0, stream>>>(Wq, bq, query, Wk, bk, Ah, Al,
                                     ws + OFF_D0, ws + OFF_W);
  k_spv    <<<512, 256, 0, stream>>>(key, value, Ah, Al, ws + OFF_D0,
                                     ws + OFF_PART, ws + OFF_SP);
  k_wred   <<<256, 256, 0, stream>>>(ws + OFF_PART, ws + OFF_W);
  k_xproj  <<<256, 256, 0, stream>>>(Wv, ws + OFF_W, bv, ws + OFF_SP, ws + OFF_X);
  k_rowdot <<<256, 256, 0, stream>>>(Wo, ws + OFF_X, bo, out);
}